// Round 2
// baseline (269.395 us; speedup 1.0000x reference)
//
#include <hip/hip_runtime.h>
#include <math.h>

// log(2*pi) + 1
#define LOG_2PI_PLUS_1 2.8378770664093454835606594728112

// Workspace layout (16 bytes, zeroed by hipMemsetAsync each launch):
//   ws[0]            : double accumulator (sum of log terms)
//   ((uint*)ws)[2]   : ticket counter for last-block-done detection
//
// Single fused kernel: grid-stride masked log-sum (float4 loads, double
// accumulation), per-wave shuffle reduce, cross-wave LDS reduce, one fp64
// atomicAdd per block, then the LAST block to finish reads the total and
// writes the scalar output. Removes the separate finalize kernel node.
__global__ __launch_bounds__(256) void fused_masked_logsum_kernel(
    const float* __restrict__ x, long long n, double* __restrict__ ws,
    float* __restrict__ out, double mn_half) {
  const long long n4 = n >> 2;
  const float4* __restrict__ x4 = (const float4*)x;
  const long long tid = (long long)blockIdx.x * blockDim.x + threadIdx.x;
  const long long stride = (long long)gridDim.x * blockDim.x;

  // 2-deep unrolled grid-stride loop: two independent float4 loads in flight
  // per iteration for more memory-level parallelism.
  double acc0 = 0.0, acc1 = 0.0;
  long long i = tid;
  for (; i + stride < n4; i += 2 * stride) {
    float4 a = x4[i];
    float4 b = x4[i + stride];
    float sa = 0.0f, sb = 0.0f;
    sa += (a.x != 0.0f) ? __logf(a.x) : 0.0f;
    sa += (a.y != 0.0f) ? __logf(a.y) : 0.0f;
    sa += (a.z != 0.0f) ? __logf(a.z) : 0.0f;
    sa += (a.w != 0.0f) ? __logf(a.w) : 0.0f;
    sb += (b.x != 0.0f) ? __logf(b.x) : 0.0f;
    sb += (b.y != 0.0f) ? __logf(b.y) : 0.0f;
    sb += (b.z != 0.0f) ? __logf(b.z) : 0.0f;
    sb += (b.w != 0.0f) ? __logf(b.w) : 0.0f;
    acc0 += (double)sa;
    acc1 += (double)sb;
  }
  for (; i < n4; i += stride) {
    float4 a = x4[i];
    float sa = 0.0f;
    sa += (a.x != 0.0f) ? __logf(a.x) : 0.0f;
    sa += (a.y != 0.0f) ? __logf(a.y) : 0.0f;
    sa += (a.z != 0.0f) ? __logf(a.z) : 0.0f;
    sa += (a.w != 0.0f) ? __logf(a.w) : 0.0f;
    acc0 += (double)sa;
  }
  double acc = acc0 + acc1;

  // scalar tail (n % 4) — n is 4096*8192 so this never runs, but stay general
  if (tid == 0) {
    for (long long j = n4 << 2; j < n; ++j) {
      float v = x[j];
      acc += (double)((v != 0.0f) ? __logf(v) : 0.0f);
    }
  }

  // 64-lane wave butterfly (wave64!)
  #pragma unroll
  for (int off = 32; off > 0; off >>= 1) {
    acc += __shfl_down(acc, off, 64);
  }

  __shared__ double smem[4];  // 256 threads / 64 lanes = 4 waves
  const int lane = threadIdx.x & 63;
  const int wave = threadIdx.x >> 6;
  if (lane == 0) smem[wave] = acc;
  __syncthreads();

  if (threadIdx.x == 0) {
    double t = smem[0] + smem[1] + smem[2] + smem[3];
    atomicAdd(ws, t);  // device-scope fp64 HW atomic on gfx950
    // Make the accumulator add visible before taking a ticket.
    __threadfence();
    unsigned int* ticket = (unsigned int*)(ws + 1);
    unsigned int prev = atomicAdd(ticket, 1u);
    if (prev == gridDim.x - 1) {
      // Last block: all partials are in. Fence then read the total.
      __threadfence();
      double sumD;
      // volatile read through atomic to defeat register caching
      sumD = __longlong_as_double(
          atomicAdd((unsigned long long*)ws, 0ull));
      double total = mn_half * LOG_2PI_PLUS_1 + 0.5 * sumD;
      out[0] = (total > 0.0) ? (float)log1p(total) : 1.0f;
    }
  }
}

extern "C" void kernel_launch(void* const* d_in, const int* in_sizes, int n_in,
                              void* d_out, int out_size, void* d_ws, size_t ws_size,
                              hipStream_t stream) {
  const float* x = (const float*)d_in[0];
  long long n = (long long)in_sizes[0];
  double* ws = (double*)d_ws;

  // ws is re-poisoned to 0xAA before every timed launch — zero accumulator
  // (8 B) + ticket counter (4 B); round to 16 B.
  hipMemsetAsync(d_ws, 0, 16, stream);

  // 2048 blocks x 256 threads: 8 blocks/CU across 256 CUs, 16 float4/thread.
  const int block = 256;
  const int grid = 2048;
  fused_masked_logsum_kernel<<<grid, block, 0, stream>>>(
      x, n, ws, (float*)d_out, 0.5 * (double)n);
}